// Round 7
// baseline (377.952 us; speedup 1.0000x reference)
//
#include <hip/hip_runtime.h>
#include <hip/hip_fp16.h>

// 2-layer GCN, N=1M (< 2^20) nodes, E=10M edges, dims 2 -> 8 -> 2.
//
// Counting sort by dst into NB=1024 buckets -> per-bucket LDS aggregation.
// Round-7: s_agg/s_deg batch-8 deep pipeline (8 NT stream loads -> 32 gathers
// -> 64 predicated LDS atomics per thread-batch; ~40 vmem in flight per wave
// vs ~10 before) to test/break the per-wave-concurrency limit. h_scatter no
// longer re-histograms (h_hist emits raw counts too).

#define NB    1024
#define SHIFT 10
#define WMASK 1023u
#define IDXMASK 0x1FFFFFu
#define EPW   16384
#define BLK   1024
#define MAXLINES ((EPW + 15 * NB) / 16)
#define BATCH 8

typedef unsigned u32x4 __attribute__((ext_vector_type(4)));

// ---------- sort pipeline ----------

__global__ __launch_bounds__(1024) void h_hist(const int* __restrict__ dst, int ne,
                                               int* __restrict__ ghist,
                                               int* __restrict__ cnts) {
    __shared__ int h[NB];
    int c = blockIdx.x;
    int c0 = c * EPW, c1 = min(c0 + EPW, ne);
    for (int b = threadIdx.x; b < NB; b += BLK) h[b] = 0;
    __syncthreads();
    int n4 = (c1 - c0) >> 2;
    const int4* d4 = (const int4*)(dst + c0);
    for (int g = threadIdx.x; g < n4; g += BLK) {
        int4 d = d4[g];
        atomicAdd(&h[d.x >> SHIFT], 1);
        atomicAdd(&h[d.y >> SHIFT], 1);
        atomicAdd(&h[d.z >> SHIFT], 1);
        atomicAdd(&h[d.w >> SHIFT], 1);
    }
    for (int e = c0 + (n4 << 2) + threadIdx.x; e < c1; e += BLK)
        atomicAdd(&h[dst[e] >> SHIFT], 1);
    __syncthreads();
    for (int b = threadIdx.x; b < NB; b += BLK) {
        int v = h[b];
        cnts [c * NB + b] = v;
        ghist[c * NB + b] = (v + 15) & ~15;        // 64B-aligned capacity
    }
}

__global__ void h_colscan(int* __restrict__ ghist, int* __restrict__ tot, int nc) {
    __shared__ int buf[1024];
    int b = blockIdx.x;
    for (int c = threadIdx.x; c < nc; c += blockDim.x) buf[c] = ghist[c * NB + b];
    __syncthreads();
    if (threadIdx.x == 0) {
        int s = 0;
        for (int c = 0; c < nc; ++c) { int v = buf[c]; buf[c] = s; s += v; }
        tot[b] = s;
    }
    __syncthreads();
    for (int c = threadIdx.x; c < nc; c += blockDim.x) ghist[c * NB + b] = buf[c];
}

__global__ void s_scan(const int* __restrict__ tot, int* __restrict__ start) {
    __shared__ int buf[NB];
    int t = threadIdx.x;               // 1024 threads
    int own = tot[t];
    buf[t] = own;
    __syncthreads();
    for (int off = 1; off < NB; off <<= 1) {
        int add = (t >= off) ? buf[t - off] : 0;
        __syncthreads();
        buf[t] += add;
        __syncthreads();
    }
    start[t] = buf[t] - own;
    if (t == NB - 1) start[NB] = buf[NB - 1];
}

// Radix-partition scatter: LDS reorder -> linear padded copy-out.
// Histogram comes precomputed from h_hist (cnts).
__global__ __launch_bounds__(1024) void h_scatter(
        const int* __restrict__ src, const int* __restrict__ dst, int ne,
        const int* __restrict__ colx, const int* __restrict__ cnts,
        const int* __restrict__ start,
        unsigned* __restrict__ sorted, unsigned sentbase) {
    __shared__ unsigned reorder[EPW];
    __shared__ unsigned short lbase[NB + 1];
    __shared__ unsigned short cbase[NB + 1];
    __shared__ int hist[NB];
    __shared__ int gbase[NB];
    __shared__ unsigned short line_bucket[MAXLINES];

    int c = blockIdx.x;
    int c0 = c * EPW;
    int cnt_edges = min(EPW, ne - c0);
    int t = threadIdx.x;

    int h = cnts[c * NB + t];          // precomputed count
    hist[t] = h;
    gbase[t] = start[t] + colx[c * NB + t];
    __syncthreads();

    // dual scan (compact count, padded capacity)
    int2* sb = (int2*)reorder;
    int cap = (h + 15) & ~15;
    sb[t] = make_int2(h, cap);
    __syncthreads();
    for (int o = 1; o < NB; o <<= 1) {
        int2 a = (t >= o) ? sb[t - o] : make_int2(0, 0);
        __syncthreads();
        sb[t].x += a.x; sb[t].y += a.y;
        __syncthreads();
    }
    int lb = sb[t].x - h;
    int cb = sb[t].y - cap;
    lbase[t] = (unsigned short)lb;
    cbase[t] = (unsigned short)cb;
    if (t == NB - 1) {
        lbase[NB] = (unsigned short)sb[t].x;
        cbase[NB] = (unsigned short)sb[t].y;
    }
    for (int k = 0; k < (cap >> 4); ++k)
        line_bucket[(cb >> 4) + k] = (unsigned short)t;
    __syncthreads();
    hist[t] = 0;                       // run counters
    __syncthreads();

    // rank + stage into LDS
    int n4 = cnt_edges >> 2;
    const int4* s4 = (const int4*)(src + c0);
    const int4* d4 = (const int4*)(dst + c0);
    for (int g = t; g < n4; g += BLK) {
        int4 s = s4[g];
        int4 d = d4[g];
        {
            int b = d.x >> SHIFT; int r = lbase[b] + atomicAdd(&hist[b], 1);
            reorder[r] = ((unsigned)s.x << SHIFT) | ((unsigned)d.x & WMASK);
        }
        {
            int b = d.y >> SHIFT; int r = lbase[b] + atomicAdd(&hist[b], 1);
            reorder[r] = ((unsigned)s.y << SHIFT) | ((unsigned)d.y & WMASK);
        }
        {
            int b = d.z >> SHIFT; int r = lbase[b] + atomicAdd(&hist[b], 1);
            reorder[r] = ((unsigned)s.z << SHIFT) | ((unsigned)d.z & WMASK);
        }
        {
            int b = d.w >> SHIFT; int r = lbase[b] + atomicAdd(&hist[b], 1);
            reorder[r] = ((unsigned)s.w << SHIFT) | ((unsigned)d.w & WMASK);
        }
    }
    for (int i = (n4 << 2) + t; i < cnt_edges; i += BLK) {
        int dd = dst[c0 + i], ss = src[c0 + i];
        int b = dd >> SHIFT; int r = lbase[b] + atomicAdd(&hist[b], 1);
        reorder[r] = ((unsigned)ss << SHIFT) | ((unsigned)dd & WMASK);
    }
    __syncthreads();

    // linear copy-out in padded index space (full-line writes only)
    int ptot = cbase[NB];
    for (int p = t; p < ptot; p += BLK) {
        int b = line_bucket[p >> 4];
        int off = p - cbase[b];
        int cnt = lbase[b + 1] - lbase[b];
        unsigned v = (off < cnt) ? reorder[lbase[b] + off]
                                 : (sentbase | (unsigned)(off & WMASK));
        sorted[gbase[b] + off] = v;
    }
}

// Per-bucket in-degree (skip sentinels) -> dinv, pre-scaled fp16 xs.
__global__ __launch_bounds__(512, 4) void s_deg(
        const unsigned* __restrict__ sorted, const int* __restrict__ start,
        const float2* __restrict__ x, float* __restrict__ dinv,
        __half2* __restrict__ xs, int nn, unsigned sentpad) {
    __shared__ int cnt[NB];
    int b = blockIdx.x;
    for (int i = threadIdx.x; i < NB; i += blockDim.x) cnt[i] = 0;
    __syncthreads();
    int e0 = start[b], e1 = start[b + 1];
    int n4 = (e1 - e0) >> 2;
    const u32x4* sv = (const u32x4*)(sorted + e0);
    for (int qb = 0; qb < n4; qb += 512 * BATCH) {
        int base_q = qb + threadIdx.x * BATCH;
        u32x4 q[BATCH];
#pragma unroll
        for (int i = 0; i < BATCH; ++i) {
            int g = base_q + i;
            q[i] = (g < n4) ? __builtin_nontemporal_load(sv + g) : (u32x4)sentpad;
        }
#pragma unroll
        for (int i = 0; i < BATCH; ++i) {
            if (!(q[i].x >> 31)) atomicAdd(&cnt[q[i].x & WMASK], 1);
            if (!(q[i].y >> 31)) atomicAdd(&cnt[q[i].y & WMASK], 1);
            if (!(q[i].z >> 31)) atomicAdd(&cnt[q[i].z & WMASK], 1);
            if (!(q[i].w >> 31)) atomicAdd(&cnt[q[i].w & WMASK], 1);
        }
    }
    __syncthreads();
    int base = b << SHIFT;
    for (int j = threadIdx.x; j < NB; j += blockDim.x) {
        int node = base + j;
        if (node < nn) {
            float di = rsqrtf((float)(cnt[j] + 1));   // +1 self-loop
            dinv[node] = di;
            float2 xv = x[node];
            xs[node] = __floats2half2_rn(xv.x * di, xv.y * di);
        }
    }
    if (b == 0 && threadIdx.x == 0) xs[nn] = __floats2half2_rn(0.f, 0.f);
}

// Per-bucket aggregation + fused epilogue, batch-8 deep pipeline.
// LAYER==1: A = di*(acc + feat[node]); h=relu(W1^T A+b1); out_h2 = (W2^T h)*di
// LAYER==2: out_f2 = di*(acc + feat[node]) + b2
template <int LAYER>
__global__ __launch_bounds__(512, 4) void s_agg(
        const unsigned* __restrict__ sorted, const int* __restrict__ start,
        const __half2* __restrict__ feat, const float* __restrict__ dinv,
        const float* __restrict__ W1, const float* __restrict__ b1,
        const float* __restrict__ W2, const float* __restrict__ b2,
        __half2* __restrict__ out_h2, float2* __restrict__ out_f2,
        int nn, unsigned sentpad) {
    __shared__ float accx[NB];
    __shared__ float accy[NB];
    int b = blockIdx.x;
    for (int i = threadIdx.x; i < NB; i += blockDim.x) { accx[i] = 0.f; accy[i] = 0.f; }
    __syncthreads();
    int e0 = start[b], e1 = start[b + 1];
    int n4 = (e1 - e0) >> 2;
    const u32x4* sv = (const u32x4*)(sorted + e0);
    const unsigned* featu = (const unsigned*)feat;
    for (int qb = 0; qb < n4; qb += 512 * BATCH) {
        int base_q = qb + threadIdx.x * BATCH;
        u32x4 q[BATCH];
#pragma unroll
        for (int i = 0; i < BATCH; ++i) {       // 8 coalesced NT stream loads
            int g = base_q + i;
            q[i] = (g < n4) ? __builtin_nontemporal_load(sv + g) : (u32x4)sentpad;
        }
        unsigned fv[BATCH][4];
#pragma unroll
        for (int i = 0; i < BATCH; ++i) {       // 32 independent gathers in flight
            fv[i][0] = featu[(q[i].x >> SHIFT) & IDXMASK];
            fv[i][1] = featu[(q[i].y >> SHIFT) & IDXMASK];
            fv[i][2] = featu[(q[i].z >> SHIFT) & IDXMASK];
            fv[i][3] = featu[(q[i].w >> SHIFT) & IDXMASK];
        }
#pragma unroll
        for (int i = 0; i < BATCH; ++i) {       // 64 predicated LDS atomics
            unsigned e[4] = {q[i].x, q[i].y, q[i].z, q[i].w};
#pragma unroll
            for (int k = 0; k < 4; ++k) {
                if (!(e[k] >> 31)) {
                    float2 f = __half22float2(*(const __half2*)&fv[i][k]);
                    int j = e[k] & WMASK;
                    atomicAdd(&accx[j], f.x);
                    atomicAdd(&accy[j], f.y);
                }
            }
        }
    }
    __syncthreads();
    int base = b << SHIFT;
    for (int j = threadIdx.x; j < NB; j += blockDim.x) {
        int node = base + j;
        if (node >= nn) continue;
        float di = dinv[node];
        float2 self = __half22float2(feat[node]);
        float ax = di * (accx[j] + self.x);
        float ay = di * (accy[j] + self.y);
        if (LAYER == 1) {
            float o0 = 0.f, o1 = 0.f;
#pragma unroll
            for (int k = 0; k < 8; ++k) {
                float hk = fmaxf(ax * W1[k] + ay * W1[8 + k] + b1[k], 0.f);
                o0 += hk * W2[2 * k + 0];
                o1 += hk * W2[2 * k + 1];
            }
            out_h2[node] = __floats2half2_rn(o0 * di, o1 * di);
        } else {
            float2 r = make_float2(ax + b2[0], ay + b2[1]);
            __builtin_nontemporal_store(r.x, &out_f2[node].x);
            __builtin_nontemporal_store(r.y, &out_f2[node].y);
        }
    }
    if (LAYER == 1 && b == 0 && threadIdx.x == 0)
        out_h2[nn] = __floats2half2_rn(0.f, 0.f);
}

// ---------- fallback (round-1 algorithm, ~24 MB scratch) ----------

__global__ void k_deg(const int* __restrict__ dst, int* __restrict__ deg, int ne) {
    int i = blockIdx.x * blockDim.x + threadIdx.x;
    int stride = gridDim.x * blockDim.x;
    for (; i < ne; i += stride) atomicAdd(&deg[dst[i]], 1);
}
__global__ void k_dinv(const int* __restrict__ deg, float* __restrict__ dinv, int nn) {
    int i = blockIdx.x * blockDim.x + threadIdx.x;
    if (i < nn) dinv[i] = rsqrtf((float)(deg[i] + 1));
}
__global__ void k_edge2(const int* __restrict__ src, const int* __restrict__ dst,
                        const float* __restrict__ feat2, const float* __restrict__ dinv,
                        float* __restrict__ agg2, int ne) {
    int i = blockIdx.x * blockDim.x + threadIdx.x;
    int stride = gridDim.x * blockDim.x;
    for (; i < ne; i += stride) {
        int s = src[i], d = dst[i];
        float nrm = dinv[s] * dinv[d];
        float2 f = reinterpret_cast<const float2*>(feat2)[s];
        unsafeAtomicAdd(&agg2[2 * d + 0], nrm * f.x);
        unsafeAtomicAdd(&agg2[2 * d + 1], nrm * f.y);
    }
}
__global__ void k_mid(const float* __restrict__ x, const float* __restrict__ aggx,
                      const float* __restrict__ dinv,
                      const float* __restrict__ W1, const float* __restrict__ b1,
                      const float* __restrict__ W2, float* __restrict__ a2, int nn) {
    int i = blockIdx.x * blockDim.x + threadIdx.x;
    if (i >= nn) return;
    float di = dinv[i], di2 = di * di;
    float2 xsv = reinterpret_cast<const float2*>(x)[i];
    float ax = aggx[2 * i + 0] + di2 * xsv.x;
    float ay = aggx[2 * i + 1] + di2 * xsv.y;
    float o0 = 0.f, o1 = 0.f;
#pragma unroll
    for (int k = 0; k < 8; ++k) {
        float hk = fmaxf(ax * W1[k] + ay * W1[8 + k] + b1[k], 0.f);
        o0 += hk * W2[2 * k + 0];
        o1 += hk * W2[2 * k + 1];
    }
    a2[2 * i + 0] = o0;
    a2[2 * i + 1] = o1;
}
__global__ void k_out(const float* __restrict__ a2, const float* __restrict__ dinv,
                      const float* __restrict__ b2, float* __restrict__ out, int nn) {
    int i = blockIdx.x * blockDim.x + threadIdx.x;
    if (i >= nn) return;
    float di = dinv[i], di2 = di * di;
    out[2 * i + 0] = out[2 * i + 0] + di2 * a2[2 * i + 0] + b2[0];
    out[2 * i + 1] = out[2 * i + 1] + di2 * a2[2 * i + 1] + b2[1];
}

extern "C" void kernel_launch(void* const* d_in, const int* in_sizes, int n_in,
                              void* d_out, int out_size, void* d_ws, size_t ws_size,
                              hipStream_t stream) {
    const float* x  = (const float*)d_in[0];
    const int*   ei = (const int*)d_in[1];
    const float* W1 = (const float*)d_in[2];
    const float* b1 = (const float*)d_in[3];
    const float* W2 = (const float*)d_in[4];
    const float* b2 = (const float*)d_in[5];
    float* out = (float*)d_out;

    const int nn = in_sizes[0] / 2;
    const int ne = in_sizes[1] / 2;
    const int* src = ei;
    const int* dst = ei + ne;

    char* ws = (char*)d_ws;
    size_t off = 0;
    auto alloc = [&](size_t bytes) -> void* {
        void* p = ws + off;
        off += (bytes + 255) & ~size_t(255);
        return p;
    };

    int nc = (ne + EPW - 1) / EPW;
    size_t sorted_elems = (size_t)ne + (size_t)nc * NB * 16;   // worst-case pads
    size_t need = sorted_elems * 4 + (size_t)nn * 4 + 2 * ((size_t)nn + 1) * 4
                + 2 * (size_t)nc * NB * 4 + (2 * NB + 2) * 4 + 16384;

    if (ws_size >= need && nc <= 1024) {
        unsigned* sorted = (unsigned*)alloc(sorted_elems * 4);
        float*    dinv   = (float*)   alloc((size_t)nn * 4);
        __half2*  xs     = (__half2*) alloc(((size_t)nn + 1) * 4);
        __half2*  xs2    = (__half2*) alloc(((size_t)nn + 1) * 4);
        int*      ghist  = (int*)     alloc((size_t)nc * NB * 4);
        int*      cnts   = (int*)     alloc((size_t)nc * NB * 4);
        int*      tot    = (int*)     alloc(NB * 4);
        int*      start  = (int*)     alloc((NB + 1) * 4);

        unsigned sentbase = 0x80000000u | ((unsigned)nn << SHIFT);

        h_hist   <<<nc, BLK, 0, stream>>>(dst, ne, ghist, cnts);
        h_colscan<<<NB, 256, 0, stream>>>(ghist, tot, nc);
        s_scan   <<<1, NB, 0, stream>>>(tot, start);
        h_scatter<<<nc, BLK, 0, stream>>>(src, dst, ne, ghist, cnts, start, sorted,
                                          sentbase);
        s_deg    <<<NB, 512, 0, stream>>>(sorted, start, (const float2*)x, dinv, xs, nn,
                                          sentbase);
        s_agg<1> <<<NB, 512, 0, stream>>>(sorted, start, xs, dinv, W1, b1, W2, b2,
                                          xs2, nullptr, nn, sentbase);
        s_agg<2> <<<NB, 512, 0, stream>>>(sorted, start, xs2, dinv, W1, b1, W2, b2,
                                          nullptr, (float2*)out, nn, sentbase);
    } else {
        // fallback: round-1 algorithm
        int*   deg  = (int*)  alloc((size_t)nn * 4);
        float* dinv = (float*)alloc((size_t)nn * 4);
        float* aggx = (float*)alloc((size_t)nn * 8);
        float* a2   = (float*)alloc((size_t)nn * 8);
        hipMemsetAsync(deg,  0, (size_t)nn * 4, stream);
        hipMemsetAsync(aggx, 0, (size_t)nn * 8, stream);
        hipMemsetAsync(d_out, 0, (size_t)nn * 8, stream);
        const int TB = 256;
        int egrid = (ne + TB - 1) / TB;
        int ngrid = (nn + TB - 1) / TB;
        k_deg  <<<egrid, TB, 0, stream>>>(dst, deg, ne);
        k_dinv <<<ngrid, TB, 0, stream>>>(deg, dinv, nn);
        k_edge2<<<egrid, TB, 0, stream>>>(src, dst, x, dinv, aggx, ne);
        k_mid  <<<ngrid, TB, 0, stream>>>(x, aggx, dinv, W1, b1, W2, a2, nn);
        k_edge2<<<egrid, TB, 0, stream>>>(src, dst, a2, dinv, out, ne);
        k_out  <<<ngrid, TB, 0, stream>>>(a2, dinv, b2, out, nn);
    }
}

// Round 8
// 308.895 us; speedup vs baseline: 1.2236x; 1.2236x over previous
//
#include <hip/hip_runtime.h>
#include <hip/hip_fp16.h>

// 2-layer GCN, N=1M (< 2^20) nodes, E=10M edges, dims 2 -> 8 -> 2.
//
// Counting sort by dst into NB=1024 buckets -> per-bucket LDS aggregation.
// Round-8: revert s_agg/s_deg to the coalesced 2-quad form (round-5 layout:
// lane-contiguous stream loads) and raise block size to 1024 (16 waves/WG,
// up to 2 WGs/CU) to A/B-test per-wave-concurrency vs fixed TA-rate as the
// gather limiter. h_scatter keeps the round-7 improvement (reuses h_hist
// counts, no re-histogram).

#define NB    1024
#define SHIFT 10
#define WMASK 1023u
#define IDXMASK 0x1FFFFFu
#define EPW   16384
#define BLK   1024
#define MAXLINES ((EPW + 15 * NB) / 16)

typedef unsigned u32x4 __attribute__((ext_vector_type(4)));

// ---------- sort pipeline ----------

__global__ __launch_bounds__(1024) void h_hist(const int* __restrict__ dst, int ne,
                                               int* __restrict__ ghist,
                                               int* __restrict__ cnts) {
    __shared__ int h[NB];
    int c = blockIdx.x;
    int c0 = c * EPW, c1 = min(c0 + EPW, ne);
    for (int b = threadIdx.x; b < NB; b += BLK) h[b] = 0;
    __syncthreads();
    int n4 = (c1 - c0) >> 2;
    const int4* d4 = (const int4*)(dst + c0);
    for (int g = threadIdx.x; g < n4; g += BLK) {
        int4 d = d4[g];
        atomicAdd(&h[d.x >> SHIFT], 1);
        atomicAdd(&h[d.y >> SHIFT], 1);
        atomicAdd(&h[d.z >> SHIFT], 1);
        atomicAdd(&h[d.w >> SHIFT], 1);
    }
    for (int e = c0 + (n4 << 2) + threadIdx.x; e < c1; e += BLK)
        atomicAdd(&h[dst[e] >> SHIFT], 1);
    __syncthreads();
    for (int b = threadIdx.x; b < NB; b += BLK) {
        int v = h[b];
        cnts [c * NB + b] = v;
        ghist[c * NB + b] = (v + 15) & ~15;        // 64B-aligned capacity
    }
}

__global__ void h_colscan(int* __restrict__ ghist, int* __restrict__ tot, int nc) {
    __shared__ int buf[1024];
    int b = blockIdx.x;
    for (int c = threadIdx.x; c < nc; c += blockDim.x) buf[c] = ghist[c * NB + b];
    __syncthreads();
    if (threadIdx.x == 0) {
        int s = 0;
        for (int c = 0; c < nc; ++c) { int v = buf[c]; buf[c] = s; s += v; }
        tot[b] = s;
    }
    __syncthreads();
    for (int c = threadIdx.x; c < nc; c += blockDim.x) ghist[c * NB + b] = buf[c];
}

__global__ void s_scan(const int* __restrict__ tot, int* __restrict__ start) {
    __shared__ int buf[NB];
    int t = threadIdx.x;               // 1024 threads
    int own = tot[t];
    buf[t] = own;
    __syncthreads();
    for (int off = 1; off < NB; off <<= 1) {
        int add = (t >= off) ? buf[t - off] : 0;
        __syncthreads();
        buf[t] += add;
        __syncthreads();
    }
    start[t] = buf[t] - own;
    if (t == NB - 1) start[NB] = buf[NB - 1];
}

// Radix-partition scatter: LDS reorder -> linear padded copy-out.
// Histogram comes precomputed from h_hist (cnts).
__global__ __launch_bounds__(1024) void h_scatter(
        const int* __restrict__ src, const int* __restrict__ dst, int ne,
        const int* __restrict__ colx, const int* __restrict__ cnts,
        const int* __restrict__ start,
        unsigned* __restrict__ sorted, unsigned sentbase) {
    __shared__ unsigned reorder[EPW];
    __shared__ unsigned short lbase[NB + 1];
    __shared__ unsigned short cbase[NB + 1];
    __shared__ int hist[NB];
    __shared__ int gbase[NB];
    __shared__ unsigned short line_bucket[MAXLINES];

    int c = blockIdx.x;
    int c0 = c * EPW;
    int cnt_edges = min(EPW, ne - c0);
    int t = threadIdx.x;

    int h = cnts[c * NB + t];          // precomputed count
    hist[t] = h;
    gbase[t] = start[t] + colx[c * NB + t];
    __syncthreads();

    // dual scan (compact count, padded capacity)
    int2* sb = (int2*)reorder;
    int cap = (h + 15) & ~15;
    sb[t] = make_int2(h, cap);
    __syncthreads();
    for (int o = 1; o < NB; o <<= 1) {
        int2 a = (t >= o) ? sb[t - o] : make_int2(0, 0);
        __syncthreads();
        sb[t].x += a.x; sb[t].y += a.y;
        __syncthreads();
    }
    int lb = sb[t].x - h;
    int cb = sb[t].y - cap;
    lbase[t] = (unsigned short)lb;
    cbase[t] = (unsigned short)cb;
    if (t == NB - 1) {
        lbase[NB] = (unsigned short)sb[t].x;
        cbase[NB] = (unsigned short)sb[t].y;
    }
    for (int k = 0; k < (cap >> 4); ++k)
        line_bucket[(cb >> 4) + k] = (unsigned short)t;
    __syncthreads();
    hist[t] = 0;                       // run counters
    __syncthreads();

    // rank + stage into LDS
    int n4 = cnt_edges >> 2;
    const int4* s4 = (const int4*)(src + c0);
    const int4* d4 = (const int4*)(dst + c0);
    for (int g = t; g < n4; g += BLK) {
        int4 s = s4[g];
        int4 d = d4[g];
        {
            int b = d.x >> SHIFT; int r = lbase[b] + atomicAdd(&hist[b], 1);
            reorder[r] = ((unsigned)s.x << SHIFT) | ((unsigned)d.x & WMASK);
        }
        {
            int b = d.y >> SHIFT; int r = lbase[b] + atomicAdd(&hist[b], 1);
            reorder[r] = ((unsigned)s.y << SHIFT) | ((unsigned)d.y & WMASK);
        }
        {
            int b = d.z >> SHIFT; int r = lbase[b] + atomicAdd(&hist[b], 1);
            reorder[r] = ((unsigned)s.z << SHIFT) | ((unsigned)d.z & WMASK);
        }
        {
            int b = d.w >> SHIFT; int r = lbase[b] + atomicAdd(&hist[b], 1);
            reorder[r] = ((unsigned)s.w << SHIFT) | ((unsigned)d.w & WMASK);
        }
    }
    for (int i = (n4 << 2) + t; i < cnt_edges; i += BLK) {
        int dd = dst[c0 + i], ss = src[c0 + i];
        int b = dd >> SHIFT; int r = lbase[b] + atomicAdd(&hist[b], 1);
        reorder[r] = ((unsigned)ss << SHIFT) | ((unsigned)dd & WMASK);
    }
    __syncthreads();

    // linear copy-out in padded index space (full-line writes only)
    int ptot = cbase[NB];
    for (int p = t; p < ptot; p += BLK) {
        int b = line_bucket[p >> 4];
        int off = p - cbase[b];
        int cnt = lbase[b + 1] - lbase[b];
        unsigned v = (off < cnt) ? reorder[lbase[b] + off]
                                 : (sentbase | (unsigned)(off & WMASK));
        sorted[gbase[b] + off] = v;
    }
}

// Per-bucket in-degree (skip sentinels) -> dinv, pre-scaled fp16 xs.
__global__ __launch_bounds__(1024) void s_deg(
        const unsigned* __restrict__ sorted, const int* __restrict__ start,
        const float2* __restrict__ x, float* __restrict__ dinv,
        __half2* __restrict__ xs, int nn, unsigned sentpad) {
    __shared__ int cnt[NB];
    int b = blockIdx.x;
    for (int i = threadIdx.x; i < NB; i += blockDim.x) cnt[i] = 0;
    __syncthreads();
    int e0 = start[b], e1 = start[b + 1];
    int n4 = (e1 - e0) >> 2;
    const u32x4* sv = (const u32x4*)(sorted + e0);
    int stride2 = blockDim.x * 2;
    for (int g = threadIdx.x; g < n4; g += stride2) {
        int g2 = g + blockDim.x;
        u32x4 a = __builtin_nontemporal_load(sv + g);
        u32x4 b4 = (g2 < n4) ? __builtin_nontemporal_load(sv + g2) : (u32x4)sentpad;
        if (!(a.x >> 31)) atomicAdd(&cnt[a.x & WMASK], 1);
        if (!(a.y >> 31)) atomicAdd(&cnt[a.y & WMASK], 1);
        if (!(a.z >> 31)) atomicAdd(&cnt[a.z & WMASK], 1);
        if (!(a.w >> 31)) atomicAdd(&cnt[a.w & WMASK], 1);
        if (!(b4.x >> 31)) atomicAdd(&cnt[b4.x & WMASK], 1);
        if (!(b4.y >> 31)) atomicAdd(&cnt[b4.y & WMASK], 1);
        if (!(b4.z >> 31)) atomicAdd(&cnt[b4.z & WMASK], 1);
        if (!(b4.w >> 31)) atomicAdd(&cnt[b4.w & WMASK], 1);
    }
    __syncthreads();
    int base = b << SHIFT;
    for (int j = threadIdx.x; j < NB; j += blockDim.x) {
        int node = base + j;
        if (node < nn) {
            float di = rsqrtf((float)(cnt[j] + 1));   // +1 self-loop
            dinv[node] = di;
            float2 xv = x[node];
            xs[node] = __floats2half2_rn(xv.x * di, xv.y * di);
        }
    }
    if (b == 0 && threadIdx.x == 0) xs[nn] = __floats2half2_rn(0.f, 0.f);
}

// Per-bucket aggregation + fused epilogue (coalesced 2-quad form).
// LAYER==1: A = di*(acc + feat[node]); h=relu(W1^T A+b1); out_h2 = (W2^T h)*di
// LAYER==2: out_f2 = di*(acc + feat[node]) + b2
template <int LAYER>
__global__ __launch_bounds__(1024) void s_agg(
        const unsigned* __restrict__ sorted, const int* __restrict__ start,
        const __half2* __restrict__ feat, const float* __restrict__ dinv,
        const float* __restrict__ W1, const float* __restrict__ b1,
        const float* __restrict__ W2, const float* __restrict__ b2,
        __half2* __restrict__ out_h2, float2* __restrict__ out_f2,
        int nn, unsigned sentpad) {
    __shared__ float accx[NB];
    __shared__ float accy[NB];
    int b = blockIdx.x;
    for (int i = threadIdx.x; i < NB; i += blockDim.x) { accx[i] = 0.f; accy[i] = 0.f; }
    __syncthreads();
    int e0 = start[b], e1 = start[b + 1];
    int n4 = (e1 - e0) >> 2;
    const u32x4* sv = (const u32x4*)(sorted + e0);
    int stride2 = blockDim.x * 2;
    for (int g = threadIdx.x; g < n4; g += stride2) {
        int g2 = g + blockDim.x;
        u32x4 a = __builtin_nontemporal_load(sv + g);
        u32x4 c = (g2 < n4) ? __builtin_nontemporal_load(sv + g2) : (u32x4)sentpad;
        // issue all 8 gathers up front (pads hit feat[nn] = one cached address)
        float2 f0 = __half22float2(feat[(a.x >> SHIFT) & IDXMASK]);
        float2 f1 = __half22float2(feat[(a.y >> SHIFT) & IDXMASK]);
        float2 f2 = __half22float2(feat[(a.z >> SHIFT) & IDXMASK]);
        float2 f3 = __half22float2(feat[(a.w >> SHIFT) & IDXMASK]);
        float2 f4 = __half22float2(feat[(c.x >> SHIFT) & IDXMASK]);
        float2 f5 = __half22float2(feat[(c.y >> SHIFT) & IDXMASK]);
        float2 f6 = __half22float2(feat[(c.z >> SHIFT) & IDXMASK]);
        float2 f7 = __half22float2(feat[(c.w >> SHIFT) & IDXMASK]);
        if (!(a.x >> 31)) { atomicAdd(&accx[a.x & WMASK], f0.x); atomicAdd(&accy[a.x & WMASK], f0.y); }
        if (!(a.y >> 31)) { atomicAdd(&accx[a.y & WMASK], f1.x); atomicAdd(&accy[a.y & WMASK], f1.y); }
        if (!(a.z >> 31)) { atomicAdd(&accx[a.z & WMASK], f2.x); atomicAdd(&accy[a.z & WMASK], f2.y); }
        if (!(a.w >> 31)) { atomicAdd(&accx[a.w & WMASK], f3.x); atomicAdd(&accy[a.w & WMASK], f3.y); }
        if (!(c.x >> 31)) { atomicAdd(&accx[c.x & WMASK], f4.x); atomicAdd(&accy[c.x & WMASK], f4.y); }
        if (!(c.y >> 31)) { atomicAdd(&accx[c.y & WMASK], f5.x); atomicAdd(&accy[c.y & WMASK], f5.y); }
        if (!(c.z >> 31)) { atomicAdd(&accx[c.z & WMASK], f6.x); atomicAdd(&accy[c.z & WMASK], f6.y); }
        if (!(c.w >> 31)) { atomicAdd(&accx[c.w & WMASK], f7.x); atomicAdd(&accy[c.w & WMASK], f7.y); }
    }
    __syncthreads();
    int base = b << SHIFT;
    for (int j = threadIdx.x; j < NB; j += blockDim.x) {
        int node = base + j;
        if (node >= nn) continue;
        float di = dinv[node];
        float2 self = __half22float2(feat[node]);
        float ax = di * (accx[j] + self.x);
        float ay = di * (accy[j] + self.y);
        if (LAYER == 1) {
            float o0 = 0.f, o1 = 0.f;
#pragma unroll
            for (int k = 0; k < 8; ++k) {
                float hk = fmaxf(ax * W1[k] + ay * W1[8 + k] + b1[k], 0.f);
                o0 += hk * W2[2 * k + 0];
                o1 += hk * W2[2 * k + 1];
            }
            out_h2[node] = __floats2half2_rn(o0 * di, o1 * di);
        } else {
            float2 r = make_float2(ax + b2[0], ay + b2[1]);
            __builtin_nontemporal_store(r.x, &out_f2[node].x);
            __builtin_nontemporal_store(r.y, &out_f2[node].y);
        }
    }
    if (LAYER == 1 && b == 0 && threadIdx.x == 0)
        out_h2[nn] = __floats2half2_rn(0.f, 0.f);
}

// ---------- fallback (round-1 algorithm, ~24 MB scratch) ----------

__global__ void k_deg(const int* __restrict__ dst, int* __restrict__ deg, int ne) {
    int i = blockIdx.x * blockDim.x + threadIdx.x;
    int stride = gridDim.x * blockDim.x;
    for (; i < ne; i += stride) atomicAdd(&deg[dst[i]], 1);
}
__global__ void k_dinv(const int* __restrict__ deg, float* __restrict__ dinv, int nn) {
    int i = blockIdx.x * blockDim.x + threadIdx.x;
    if (i < nn) dinv[i] = rsqrtf((float)(deg[i] + 1));
}
__global__ void k_edge2(const int* __restrict__ src, const int* __restrict__ dst,
                        const float* __restrict__ feat2, const float* __restrict__ dinv,
                        float* __restrict__ agg2, int ne) {
    int i = blockIdx.x * blockDim.x + threadIdx.x;
    int stride = gridDim.x * blockDim.x;
    for (; i < ne; i += stride) {
        int s = src[i], d = dst[i];
        float nrm = dinv[s] * dinv[d];
        float2 f = reinterpret_cast<const float2*>(feat2)[s];
        unsafeAtomicAdd(&agg2[2 * d + 0], nrm * f.x);
        unsafeAtomicAdd(&agg2[2 * d + 1], nrm * f.y);
    }
}
__global__ void k_mid(const float* __restrict__ x, const float* __restrict__ aggx,
                      const float* __restrict__ dinv,
                      const float* __restrict__ W1, const float* __restrict__ b1,
                      const float* __restrict__ W2, float* __restrict__ a2, int nn) {
    int i = blockIdx.x * blockDim.x + threadIdx.x;
    if (i >= nn) return;
    float di = dinv[i], di2 = di * di;
    float2 xsv = reinterpret_cast<const float2*>(x)[i];
    float ax = aggx[2 * i + 0] + di2 * xsv.x;
    float ay = aggx[2 * i + 1] + di2 * xsv.y;
    float o0 = 0.f, o1 = 0.f;
#pragma unroll
    for (int k = 0; k < 8; ++k) {
        float hk = fmaxf(ax * W1[k] + ay * W1[8 + k] + b1[k], 0.f);
        o0 += hk * W2[2 * k + 0];
        o1 += hk * W2[2 * k + 1];
    }
    a2[2 * i + 0] = o0;
    a2[2 * i + 1] = o1;
}
__global__ void k_out(const float* __restrict__ a2, const float* __restrict__ dinv,
                      const float* __restrict__ b2, float* __restrict__ out, int nn) {
    int i = blockIdx.x * blockDim.x + threadIdx.x;
    if (i >= nn) return;
    float di = dinv[i], di2 = di * di;
    out[2 * i + 0] = out[2 * i + 0] + di2 * a2[2 * i + 0] + b2[0];
    out[2 * i + 1] = out[2 * i + 1] + di2 * a2[2 * i + 1] + b2[1];
}

extern "C" void kernel_launch(void* const* d_in, const int* in_sizes, int n_in,
                              void* d_out, int out_size, void* d_ws, size_t ws_size,
                              hipStream_t stream) {
    const float* x  = (const float*)d_in[0];
    const int*   ei = (const int*)d_in[1];
    const float* W1 = (const float*)d_in[2];
    const float* b1 = (const float*)d_in[3];
    const float* W2 = (const float*)d_in[4];
    const float* b2 = (const float*)d_in[5];
    float* out = (float*)d_out;

    const int nn = in_sizes[0] / 2;
    const int ne = in_sizes[1] / 2;
    const int* src = ei;
    const int* dst = ei + ne;

    char* ws = (char*)d_ws;
    size_t off = 0;
    auto alloc = [&](size_t bytes) -> void* {
        void* p = ws + off;
        off += (bytes + 255) & ~size_t(255);
        return p;
    };

    int nc = (ne + EPW - 1) / EPW;
    size_t sorted_elems = (size_t)ne + (size_t)nc * NB * 16;   // worst-case pads
    size_t need = sorted_elems * 4 + (size_t)nn * 4 + 2 * ((size_t)nn + 1) * 4
                + 2 * (size_t)nc * NB * 4 + (2 * NB + 2) * 4 + 16384;

    if (ws_size >= need && nc <= 1024) {
        unsigned* sorted = (unsigned*)alloc(sorted_elems * 4);
        float*    dinv   = (float*)   alloc((size_t)nn * 4);
        __half2*  xs     = (__half2*) alloc(((size_t)nn + 1) * 4);
        __half2*  xs2    = (__half2*) alloc(((size_t)nn + 1) * 4);
        int*      ghist  = (int*)     alloc((size_t)nc * NB * 4);
        int*      cnts   = (int*)     alloc((size_t)nc * NB * 4);
        int*      tot    = (int*)     alloc(NB * 4);
        int*      start  = (int*)     alloc((NB + 1) * 4);

        unsigned sentbase = 0x80000000u | ((unsigned)nn << SHIFT);

        h_hist   <<<nc, BLK, 0, stream>>>(dst, ne, ghist, cnts);
        h_colscan<<<NB, 256, 0, stream>>>(ghist, tot, nc);
        s_scan   <<<1, NB, 0, stream>>>(tot, start);
        h_scatter<<<nc, BLK, 0, stream>>>(src, dst, ne, ghist, cnts, start, sorted,
                                          sentbase);
        s_deg    <<<NB, 1024, 0, stream>>>(sorted, start, (const float2*)x, dinv, xs, nn,
                                           sentbase);
        s_agg<1> <<<NB, 1024, 0, stream>>>(sorted, start, xs, dinv, W1, b1, W2, b2,
                                           xs2, nullptr, nn, sentbase);
        s_agg<2> <<<NB, 1024, 0, stream>>>(sorted, start, xs2, dinv, W1, b1, W2, b2,
                                           nullptr, (float2*)out, nn, sentbase);
    } else {
        // fallback: round-1 algorithm
        int*   deg  = (int*)  alloc((size_t)nn * 4);
        float* dinv = (float*)alloc((size_t)nn * 4);
        float* aggx = (float*)alloc((size_t)nn * 8);
        float* a2   = (float*)alloc((size_t)nn * 8);
        hipMemsetAsync(deg,  0, (size_t)nn * 4, stream);
        hipMemsetAsync(aggx, 0, (size_t)nn * 8, stream);
        hipMemsetAsync(d_out, 0, (size_t)nn * 8, stream);
        const int TB = 256;
        int egrid = (ne + TB - 1) / TB;
        int ngrid = (nn + TB - 1) / TB;
        k_deg  <<<egrid, TB, 0, stream>>>(dst, deg, ne);
        k_dinv <<<ngrid, TB, 0, stream>>>(deg, dinv, nn);
        k_edge2<<<egrid, TB, 0, stream>>>(src, dst, x, dinv, aggx, ne);
        k_mid  <<<ngrid, TB, 0, stream>>>(x, aggx, dinv, W1, b1, W2, a2, nn);
        k_edge2<<<egrid, TB, 0, stream>>>(src, dst, a2, dinv, out, ne);
        k_out  <<<ngrid, TB, 0, stream>>>(a2, dinv, b2, out, nn);
    }
}

// Round 10
// 265.265 us; speedup vs baseline: 1.4248x; 1.1645x over previous
//
#include <hip/hip_runtime.h>
#include <hip/hip_fp16.h>

// 2-layer GCN, N=1M (< 2^20) nodes, E=10M edges, dims 2 -> 8 -> 2.
//
// Counting sort by dst into NB=1024 buckets -> per-bucket LDS aggregation.
// Round-10: (1) packed 64-bit fixed-point LDS accumulation: ONE
// atomicAdd(u64) (ds_add_u64) per edge instead of two fp32 LDS atomics.
// Feature tables are pre-quantized: q(v)=rint((v+128)*8192), lo=ch0 hi=ch1;
// offset keeps halves non-negative (no borrow), epilogue subtracts
// cnt*2^20 in exact integer arithmetic. Quantization err ~1.2e-4.
// (2) EPW 16384->32768: pad inflation 47%->23%, downstream passes -13%.

#define NB    1024
#define SHIFT 10
#define WMASK 1023u
#define IDXMASK 0x1FFFFFu
#define EPW   32768
#define BLK   1024
#define MAXLINES ((EPW + 15 * NB) / 16)   // 3008
#define QSCALE 8192.0f
#define QOFF   128.0f
#define QBIAS  1048576LL                  // QOFF*QSCALE = 2^20

typedef unsigned u32x4 __attribute__((ext_vector_type(4)));

__device__ inline unsigned long long pack2(float vx, float vy) {
    float cx = fminf(fmaxf(vx + QOFF, 0.f), 2.f * QOFF);
    float cy = fminf(fmaxf(vy + QOFF, 0.f), 2.f * QOFF);
    unsigned qx = (unsigned)rintf(cx * QSCALE);
    unsigned qy = (unsigned)rintf(cy * QSCALE);
    return ((unsigned long long)qy << 32) | qx;
}

// ---------- sort pipeline ----------

__global__ __launch_bounds__(1024) void h_hist(const int* __restrict__ dst, int ne,
                                               int* __restrict__ ghist,
                                               int* __restrict__ cnts) {
    __shared__ int h[NB];
    int c = blockIdx.x;
    int c0 = c * EPW, c1 = min(c0 + EPW, ne);
    for (int b = threadIdx.x; b < NB; b += BLK) h[b] = 0;
    __syncthreads();
    int n4 = (c1 - c0) >> 2;
    const int4* d4 = (const int4*)(dst + c0);
    for (int g = threadIdx.x; g < n4; g += BLK) {
        int4 d = d4[g];
        atomicAdd(&h[d.x >> SHIFT], 1);
        atomicAdd(&h[d.y >> SHIFT], 1);
        atomicAdd(&h[d.z >> SHIFT], 1);
        atomicAdd(&h[d.w >> SHIFT], 1);
    }
    for (int e = c0 + (n4 << 2) + threadIdx.x; e < c1; e += BLK)
        atomicAdd(&h[dst[e] >> SHIFT], 1);
    __syncthreads();
    for (int b = threadIdx.x; b < NB; b += BLK) {
        int v = h[b];
        cnts [c * NB + b] = v;
        ghist[c * NB + b] = (v + 15) & ~15;        // 64B-aligned capacity
    }
}

__global__ void h_colscan(int* __restrict__ ghist, int* __restrict__ tot, int nc) {
    __shared__ int buf[1024];
    int b = blockIdx.x;
    for (int c = threadIdx.x; c < nc; c += blockDim.x) buf[c] = ghist[c * NB + b];
    __syncthreads();
    if (threadIdx.x == 0) {
        int s = 0;
        for (int c = 0; c < nc; ++c) { int v = buf[c]; buf[c] = s; s += v; }
        tot[b] = s;
    }
    __syncthreads();
    for (int c = threadIdx.x; c < nc; c += blockDim.x) ghist[c * NB + b] = buf[c];
}

__global__ void s_scan(const int* __restrict__ tot, int* __restrict__ start) {
    __shared__ int buf[NB];
    int t = threadIdx.x;               // 1024 threads
    int own = tot[t];
    buf[t] = own;
    __syncthreads();
    for (int off = 1; off < NB; off <<= 1) {
        int add = (t >= off) ? buf[t - off] : 0;
        __syncthreads();
        buf[t] += add;
        __syncthreads();
    }
    start[t] = buf[t] - own;
    if (t == NB - 1) start[NB] = buf[NB - 1];
}

// Radix-partition scatter: LDS reorder -> linear padded copy-out.
// Histogram precomputed by h_hist. ~146KB LDS, 1 WG/CU.
__global__ __launch_bounds__(1024) void h_scatter(
        const int* __restrict__ src, const int* __restrict__ dst, int ne,
        const int* __restrict__ colx, const int* __restrict__ cnts,
        const int* __restrict__ start,
        unsigned* __restrict__ sorted, unsigned sentbase) {
    __shared__ unsigned reorder[EPW];          // 128KB
    __shared__ unsigned short lbase[NB + 1];
    __shared__ unsigned short cbase[NB + 1];
    __shared__ int hist[NB];
    __shared__ int gbase[NB];
    __shared__ unsigned short line_bucket[MAXLINES];

    int c = blockIdx.x;
    int c0 = c * EPW;
    int cnt_edges = min(EPW, ne - c0);
    int t = threadIdx.x;

    int h = cnts[c * NB + t];          // precomputed count
    hist[t] = h;
    gbase[t] = start[t] + colx[c * NB + t];
    __syncthreads();

    // dual scan (compact count, padded capacity)
    int2* sb = (int2*)reorder;
    int cap = (h + 15) & ~15;
    sb[t] = make_int2(h, cap);
    __syncthreads();
    for (int o = 1; o < NB; o <<= 1) {
        int2 a = (t >= o) ? sb[t - o] : make_int2(0, 0);
        __syncthreads();
        sb[t].x += a.x; sb[t].y += a.y;
        __syncthreads();
    }
    int lb = sb[t].x - h;
    int cb = sb[t].y - cap;
    lbase[t] = (unsigned short)lb;
    cbase[t] = (unsigned short)cb;
    if (t == NB - 1) {
        lbase[NB] = (unsigned short)sb[t].x;
        cbase[NB] = (unsigned short)sb[t].y;
    }
    for (int k = 0; k < (cap >> 4); ++k)
        line_bucket[(cb >> 4) + k] = (unsigned short)t;
    __syncthreads();
    hist[t] = 0;                       // run counters
    __syncthreads();

    // rank + stage into LDS
    int n4 = cnt_edges >> 2;
    const int4* s4 = (const int4*)(src + c0);
    const int4* d4 = (const int4*)(dst + c0);
    for (int g = t; g < n4; g += BLK) {
        int4 s = s4[g];
        int4 d = d4[g];
        {
            int b = d.x >> SHIFT; int r = lbase[b] + atomicAdd(&hist[b], 1);
            reorder[r] = ((unsigned)s.x << SHIFT) | ((unsigned)d.x & WMASK);
        }
        {
            int b = d.y >> SHIFT; int r = lbase[b] + atomicAdd(&hist[b], 1);
            reorder[r] = ((unsigned)s.y << SHIFT) | ((unsigned)d.y & WMASK);
        }
        {
            int b = d.z >> SHIFT; int r = lbase[b] + atomicAdd(&hist[b], 1);
            reorder[r] = ((unsigned)s.z << SHIFT) | ((unsigned)d.z & WMASK);
        }
        {
            int b = d.w >> SHIFT; int r = lbase[b] + atomicAdd(&hist[b], 1);
            reorder[r] = ((unsigned)s.w << SHIFT) | ((unsigned)d.w & WMASK);
        }
    }
    for (int i = (n4 << 2) + t; i < cnt_edges; i += BLK) {
        int dd = dst[c0 + i], ss = src[c0 + i];
        int b = dd >> SHIFT; int r = lbase[b] + atomicAdd(&hist[b], 1);
        reorder[r] = ((unsigned)ss << SHIFT) | ((unsigned)dd & WMASK);
    }
    __syncthreads();

    // linear copy-out in padded index space (full-line writes only)
    int ptot = cbase[NB];
    for (int p = t; p < ptot; p += BLK) {
        int b = line_bucket[p >> 4];
        int off = p - cbase[b];
        int cnt = lbase[b + 1] - lbase[b];
        unsigned v = (off < cnt) ? reorder[lbase[b] + off]
                                 : (sentbase | (unsigned)(off & WMASK));
        sorted[gbase[b] + off] = v;
    }
}

// Per-bucket in-degree (skip sentinels) -> dinv, pre-quantized packed xs64.
__global__ __launch_bounds__(1024) void s_deg(
        const unsigned* __restrict__ sorted, const int* __restrict__ start,
        const float2* __restrict__ x, float* __restrict__ dinv,
        unsigned long long* __restrict__ xs64, int nn, unsigned sentpad) {
    __shared__ int cnt[NB];
    int b = blockIdx.x;
    for (int i = threadIdx.x; i < NB; i += blockDim.x) cnt[i] = 0;
    __syncthreads();
    int e0 = start[b], e1 = start[b + 1];
    int n4 = (e1 - e0) >> 2;
    const u32x4* sv = (const u32x4*)(sorted + e0);
    int stride2 = blockDim.x * 2;
    for (int g = threadIdx.x; g < n4; g += stride2) {
        int g2 = g + blockDim.x;
        u32x4 a = __builtin_nontemporal_load(sv + g);
        u32x4 b4 = (g2 < n4) ? __builtin_nontemporal_load(sv + g2) : (u32x4)sentpad;
        if (!(a.x >> 31)) atomicAdd(&cnt[a.x & WMASK], 1);
        if (!(a.y >> 31)) atomicAdd(&cnt[a.y & WMASK], 1);
        if (!(a.z >> 31)) atomicAdd(&cnt[a.z & WMASK], 1);
        if (!(a.w >> 31)) atomicAdd(&cnt[a.w & WMASK], 1);
        if (!(b4.x >> 31)) atomicAdd(&cnt[b4.x & WMASK], 1);
        if (!(b4.y >> 31)) atomicAdd(&cnt[b4.y & WMASK], 1);
        if (!(b4.z >> 31)) atomicAdd(&cnt[b4.z & WMASK], 1);
        if (!(b4.w >> 31)) atomicAdd(&cnt[b4.w & WMASK], 1);
    }
    __syncthreads();
    int base = b << SHIFT;
    for (int j = threadIdx.x; j < NB; j += blockDim.x) {
        int node = base + j;
        if (node < nn) {
            float di = rsqrtf((float)(cnt[j] + 1));   // +1 self-loop
            dinv[node] = di;
            float2 xv = x[node];
            xs64[node] = pack2(xv.x * di, xv.y * di);
        }
    }
}

// Per-bucket aggregation + fused epilogue. ONE u64 LDS atomic per edge
// (ds_add_u64) on the pre-quantized packed feature.
// LAYER==1: A = di*(sum + self); h=relu(W1^T A+b1); out64 = pack((W2^T h)*di)
// LAYER==2: out_f2 = di*(sum + self) + b2
template <int LAYER>
__global__ __launch_bounds__(1024) void s_agg(
        const unsigned* __restrict__ sorted, const int* __restrict__ start,
        const unsigned long long* __restrict__ feat64, const float* __restrict__ dinv,
        const float* __restrict__ W1, const float* __restrict__ b1,
        const float* __restrict__ W2, const float* __restrict__ b2,
        unsigned long long* __restrict__ out64, float2* __restrict__ out_f2,
        int nn, unsigned sentpad) {
    __shared__ unsigned long long acc64[NB];
    int b = blockIdx.x;
    for (int i = threadIdx.x; i < NB; i += blockDim.x) acc64[i] = 0ULL;
    __syncthreads();
    int e0 = start[b], e1 = start[b + 1];
    int n4 = (e1 - e0) >> 2;
    const u32x4* sv = (const u32x4*)(sorted + e0);
    int stride2 = blockDim.x * 2;
    for (int g = threadIdx.x; g < n4; g += stride2) {
        int g2 = g + blockDim.x;
        u32x4 a = __builtin_nontemporal_load(sv + g);
        u32x4 c = (g2 < n4) ? __builtin_nontemporal_load(sv + g2) : (u32x4)sentpad;
        if (!(a.x >> 31)) atomicAdd(&acc64[a.x & WMASK], feat64[(a.x >> SHIFT) & IDXMASK]);
        if (!(a.y >> 31)) atomicAdd(&acc64[a.y & WMASK], feat64[(a.y >> SHIFT) & IDXMASK]);
        if (!(a.z >> 31)) atomicAdd(&acc64[a.z & WMASK], feat64[(a.z >> SHIFT) & IDXMASK]);
        if (!(a.w >> 31)) atomicAdd(&acc64[a.w & WMASK], feat64[(a.w >> SHIFT) & IDXMASK]);
        if (!(c.x >> 31)) atomicAdd(&acc64[c.x & WMASK], feat64[(c.x >> SHIFT) & IDXMASK]);
        if (!(c.y >> 31)) atomicAdd(&acc64[c.y & WMASK], feat64[(c.y >> SHIFT) & IDXMASK]);
        if (!(c.z >> 31)) atomicAdd(&acc64[c.z & WMASK], feat64[(c.z >> SHIFT) & IDXMASK]);
        if (!(c.w >> 31)) atomicAdd(&acc64[c.w & WMASK], feat64[(c.w >> SHIFT) & IDXMASK]);
    }
    __syncthreads();
    int base = b << SHIFT;
    for (int j = threadIdx.x; j < NB; j += blockDim.x) {
        int node = base + j;
        if (node >= nn) continue;
        float di = dinv[node];
        int cnt = (int)rintf(1.0f / (di * di)) - 1;   // in-degree (exact)
        unsigned long long p = acc64[j];
        unsigned long long s64 = feat64[node];
        // integer-exact bias removal: sum over cnt edges + self (bias 1)
        long long bsum = (long long)(cnt) * QBIAS;
        float sx = (float)((long long)(p & 0xffffffffULL) - bsum) * (1.0f / QSCALE);
        float sy = (float)((long long)(p >> 32)           - bsum) * (1.0f / QSCALE);
        float fx = (float)((long long)(s64 & 0xffffffffULL) - QBIAS) * (1.0f / QSCALE);
        float fy = (float)((long long)(s64 >> 32)           - QBIAS) * (1.0f / QSCALE);
        float ax = di * (sx + fx);
        float ay = di * (sy + fy);
        if (LAYER == 1) {
            float o0 = 0.f, o1 = 0.f;
#pragma unroll
            for (int k = 0; k < 8; ++k) {
                float hk = fmaxf(ax * W1[k] + ay * W1[8 + k] + b1[k], 0.f);
                o0 += hk * W2[2 * k + 0];
                o1 += hk * W2[2 * k + 1];
            }
            out64[node] = pack2(o0 * di, o1 * di);
        } else {
            float2 r = make_float2(ax + b2[0], ay + b2[1]);
            __builtin_nontemporal_store(r.x, &out_f2[node].x);
            __builtin_nontemporal_store(r.y, &out_f2[node].y);
        }
    }
}

// ---------- fallback (round-1 algorithm, ~24 MB scratch) ----------

__global__ void k_deg(const int* __restrict__ dst, int* __restrict__ deg, int ne) {
    int i = blockIdx.x * blockDim.x + threadIdx.x;
    int stride = gridDim.x * blockDim.x;
    for (; i < ne; i += stride) atomicAdd(&deg[dst[i]], 1);
}
__global__ void k_dinv(const int* __restrict__ deg, float* __restrict__ dinv, int nn) {
    int i = blockIdx.x * blockDim.x + threadIdx.x;
    if (i < nn) dinv[i] = rsqrtf((float)(deg[i] + 1));
}
__global__ void k_edge2(const int* __restrict__ src, const int* __restrict__ dst,
                        const float* __restrict__ feat2, const float* __restrict__ dinv,
                        float* __restrict__ agg2, int ne) {
    int i = blockIdx.x * blockDim.x + threadIdx.x;
    int stride = gridDim.x * blockDim.x;
    for (; i < ne; i += stride) {
        int s = src[i], d = dst[i];
        float nrm = dinv[s] * dinv[d];
        float2 f = reinterpret_cast<const float2*>(feat2)[s];
        unsafeAtomicAdd(&agg2[2 * d + 0], nrm * f.x);
        unsafeAtomicAdd(&agg2[2 * d + 1], nrm * f.y);
    }
}
__global__ void k_mid(const float* __restrict__ x, const float* __restrict__ aggx,
                      const float* __restrict__ dinv,
                      const float* __restrict__ W1, const float* __restrict__ b1,
                      const float* __restrict__ W2, float* __restrict__ a2, int nn) {
    int i = blockIdx.x * blockDim.x + threadIdx.x;
    if (i >= nn) return;
    float di = dinv[i], di2 = di * di;
    float2 xsv = reinterpret_cast<const float2*>(x)[i];
    float ax = aggx[2 * i + 0] + di2 * xsv.x;
    float ay = aggx[2 * i + 1] + di2 * xsv.y;
    float o0 = 0.f, o1 = 0.f;
#pragma unroll
    for (int k = 0; k < 8; ++k) {
        float hk = fmaxf(ax * W1[k] + ay * W1[8 + k] + b1[k], 0.f);
        o0 += hk * W2[2 * k + 0];
        o1 += hk * W2[2 * k + 1];
    }
    a2[2 * i + 0] = o0;
    a2[2 * i + 1] = o1;
}
__global__ void k_out(const float* __restrict__ a2, const float* __restrict__ dinv,
                      const float* __restrict__ b2, float* __restrict__ out, int nn) {
    int i = blockIdx.x * blockDim.x + threadIdx.x;
    if (i >= nn) return;
    float di = dinv[i], di2 = di * di;
    out[2 * i + 0] = out[2 * i + 0] + di2 * a2[2 * i + 0] + b2[0];
    out[2 * i + 1] = out[2 * i + 1] + di2 * a2[2 * i + 1] + b2[1];
}

extern "C" void kernel_launch(void* const* d_in, const int* in_sizes, int n_in,
                              void* d_out, int out_size, void* d_ws, size_t ws_size,
                              hipStream_t stream) {
    const float* x  = (const float*)d_in[0];
    const int*   ei = (const int*)d_in[1];
    const float* W1 = (const float*)d_in[2];
    const float* b1 = (const float*)d_in[3];
    const float* W2 = (const float*)d_in[4];
    const float* b2 = (const float*)d_in[5];
    float* out = (float*)d_out;

    const int nn = in_sizes[0] / 2;
    const int ne = in_sizes[1] / 2;
    const int* src = ei;
    const int* dst = ei + ne;

    char* ws = (char*)d_ws;
    size_t off = 0;
    auto alloc = [&](size_t bytes) -> void* {
        void* p = ws + off;
        off += (bytes + 255) & ~size_t(255);
        return p;
    };

    int nc = (ne + EPW - 1) / EPW;
    size_t sorted_elems = (size_t)ne + (size_t)nc * NB * 16;   // worst-case pads
    size_t need = sorted_elems * 4 + (size_t)nn * 4 + 2 * ((size_t)nn + 1) * 8
                + 2 * (size_t)nc * NB * 4 + (2 * NB + 2) * 4 + 16384;

    if (ws_size >= need && nc <= 1024) {
        unsigned*           sorted = (unsigned*)           alloc(sorted_elems * 4);
        float*              dinv   = (float*)              alloc((size_t)nn * 4);
        unsigned long long* xs64   = (unsigned long long*) alloc(((size_t)nn + 1) * 8);
        unsigned long long* xs2_64 = (unsigned long long*) alloc(((size_t)nn + 1) * 8);
        int*                ghist  = (int*)                alloc((size_t)nc * NB * 4);
        int*                cnts   = (int*)                alloc((size_t)nc * NB * 4);
        int*                tot    = (int*)                alloc(NB * 4);
        int*                start  = (int*)                alloc((NB + 1) * 4);

        unsigned sentbase = 0x80000000u | ((unsigned)nn << SHIFT);

        h_hist   <<<nc, BLK, 0, stream>>>(dst, ne, ghist, cnts);
        h_colscan<<<NB, 256, 0, stream>>>(ghist, tot, nc);
        s_scan   <<<1, NB, 0, stream>>>(tot, start);
        h_scatter<<<nc, BLK, 0, stream>>>(src, dst, ne, ghist, cnts, start, sorted,
                                          sentbase);
        s_deg    <<<NB, 1024, 0, stream>>>(sorted, start, (const float2*)x, dinv, xs64,
                                           nn, sentbase);
        s_agg<1> <<<NB, 1024, 0, stream>>>(sorted, start, xs64, dinv, W1, b1, W2, b2,
                                           xs2_64, nullptr, nn, sentbase);
        s_agg<2> <<<NB, 1024, 0, stream>>>(sorted, start, xs2_64, dinv, W1, b1, W2, b2,
                                           nullptr, (float2*)out, nn, sentbase);
    } else {
        // fallback: round-1 algorithm
        int*   deg  = (int*)  alloc((size_t)nn * 4);
        float* dinv = (float*)alloc((size_t)nn * 4);
        float* aggx = (float*)alloc((size_t)nn * 8);
        float* a2   = (float*)alloc((size_t)nn * 8);
        hipMemsetAsync(deg,  0, (size_t)nn * 4, stream);
        hipMemsetAsync(aggx, 0, (size_t)nn * 8, stream);
        hipMemsetAsync(d_out, 0, (size_t)nn * 8, stream);
        const int TB = 256;
        int egrid = (ne + TB - 1) / TB;
        int ngrid = (nn + TB - 1) / TB;
        k_deg  <<<egrid, TB, 0, stream>>>(dst, deg, ne);
        k_dinv <<<ngrid, TB, 0, stream>>>(deg, dinv, nn);
        k_edge2<<<egrid, TB, 0, stream>>>(src, dst, x, dinv, aggx, ne);
        k_mid  <<<ngrid, TB, 0, stream>>>(x, aggx, dinv, W1, b1, W2, a2, nn);
        k_edge2<<<egrid, TB, 0, stream>>>(src, dst, a2, dinv, out, ne);
        k_out  <<<ngrid, TB, 0, stream>>>(a2, dinv, b2, out, nn);
    }
}

// Round 11
// 260.358 us; speedup vs baseline: 1.4517x; 1.0188x over previous
//
#include <hip/hip_runtime.h>
#include <hip/hip_fp16.h>

// 2-layer GCN, N=1M (< 2^20) nodes, E=10M edges, dims 2 -> 8 -> 2.
//
// Counting sort by dst into NB=512 buckets of 2048 nodes -> per-bucket LDS
// aggregation via ONE packed u64 fixed-point atomic per edge.
// Round-11: NB 1024->512 (SHIFT=11): pad inflation 23%->12%, shrinking every
// edge-stream pass ~9%. Sentinel pads use src-index 0 (cached gather,
// predicated atomic). Established invariants kept: line-aligned private
// scatter regions, LDS radix-partition scatter, pre-quantized u64 tables
// (q(v)=rint((v+128)*8192), integer-exact bias removal in epilogue).

#define NB    512
#define SHIFT 11
#define WMASK 2047u
#define IDXMASK 0xFFFFFu      // 20-bit source index
#define EPW   32768
#define BLK   1024
#define MAXLINES ((EPW + 15 * NB) / 16)   // 2528
#define QSCALE 8192.0f
#define QOFF   128.0f
#define QBIAS  1048576LL                  // QOFF*QSCALE = 2^20

typedef unsigned u32x4 __attribute__((ext_vector_type(4)));

__device__ inline unsigned long long pack2(float vx, float vy) {
    float cx = fminf(fmaxf(vx + QOFF, 0.f), 2.f * QOFF);
    float cy = fminf(fmaxf(vy + QOFF, 0.f), 2.f * QOFF);
    unsigned qx = (unsigned)rintf(cx * QSCALE);
    unsigned qy = (unsigned)rintf(cy * QSCALE);
    return ((unsigned long long)qy << 32) | qx;
}

// ---------- sort pipeline ----------

__global__ __launch_bounds__(1024) void h_hist(const int* __restrict__ dst, int ne,
                                               int* __restrict__ ghist,
                                               int* __restrict__ cnts) {
    __shared__ int h[NB];
    int c = blockIdx.x;
    int c0 = c * EPW, c1 = min(c0 + EPW, ne);
    for (int b = threadIdx.x; b < NB; b += BLK) h[b] = 0;
    __syncthreads();
    int n4 = (c1 - c0) >> 2;
    const int4* d4 = (const int4*)(dst + c0);
    for (int g = threadIdx.x; g < n4; g += BLK) {
        int4 d = d4[g];
        atomicAdd(&h[d.x >> SHIFT], 1);
        atomicAdd(&h[d.y >> SHIFT], 1);
        atomicAdd(&h[d.z >> SHIFT], 1);
        atomicAdd(&h[d.w >> SHIFT], 1);
    }
    for (int e = c0 + (n4 << 2) + threadIdx.x; e < c1; e += BLK)
        atomicAdd(&h[dst[e] >> SHIFT], 1);
    __syncthreads();
    for (int b = threadIdx.x; b < NB; b += BLK) {
        int v = h[b];
        cnts [c * NB + b] = v;
        ghist[c * NB + b] = (v + 15) & ~15;        // 64B-aligned capacity
    }
}

__global__ void h_colscan(int* __restrict__ ghist, int* __restrict__ tot, int nc) {
    __shared__ int buf[1024];
    int b = blockIdx.x;
    for (int c = threadIdx.x; c < nc; c += blockDim.x) buf[c] = ghist[c * NB + b];
    __syncthreads();
    if (threadIdx.x == 0) {
        int s = 0;
        for (int c = 0; c < nc; ++c) { int v = buf[c]; buf[c] = s; s += v; }
        tot[b] = s;
    }
    __syncthreads();
    for (int c = threadIdx.x; c < nc; c += blockDim.x) ghist[c * NB + b] = buf[c];
}

__global__ void s_scan(const int* __restrict__ tot, int* __restrict__ start) {
    __shared__ int buf[NB];
    int t = threadIdx.x;               // launched with NB threads
    int own = tot[t];
    buf[t] = own;
    __syncthreads();
    for (int off = 1; off < NB; off <<= 1) {
        int add = (t >= off) ? buf[t - off] : 0;
        __syncthreads();
        buf[t] += add;
        __syncthreads();
    }
    start[t] = buf[t] - own;
    if (t == NB - 1) start[NB] = buf[NB - 1];
}

// Radix-partition scatter: LDS reorder -> linear padded copy-out.
// Histogram precomputed by h_hist. ~134KB LDS, 1 WG/CU.
__global__ __launch_bounds__(1024) void h_scatter(
        const int* __restrict__ src, const int* __restrict__ dst, int ne,
        const int* __restrict__ colx, const int* __restrict__ cnts,
        const int* __restrict__ start,
        unsigned* __restrict__ sorted, unsigned sentbase) {
    __shared__ unsigned reorder[EPW];          // 128KB
    __shared__ unsigned short lbase[NB + 1];
    __shared__ unsigned short cbase[NB + 1];
    __shared__ int hist[NB];
    __shared__ int gbase[NB];
    __shared__ unsigned short line_bucket[MAXLINES];

    int c = blockIdx.x;
    int c0 = c * EPW;
    int cnt_edges = min(EPW, ne - c0);
    int t = threadIdx.x;

    if (t < NB) {
        int h = cnts[c * NB + t];
        hist[t] = h;
        gbase[t] = start[t] + colx[c * NB + t];
    }
    __syncthreads();

    // dual scan (compact count, padded capacity) over NB=512 entries
    int2* sb = (int2*)reorder;
    int h = 0, cap = 0;
    if (t < NB) {
        h = hist[t];
        cap = (h + 15) & ~15;
        sb[t] = make_int2(h, cap);
    }
    __syncthreads();
    for (int o = 1; o < NB; o <<= 1) {
        int2 a = (t >= o && t < NB) ? sb[t - o] : make_int2(0, 0);
        __syncthreads();
        if (t < NB) { sb[t].x += a.x; sb[t].y += a.y; }
        __syncthreads();
    }
    if (t < NB) {
        int lb = sb[t].x - h;
        int cb = sb[t].y - cap;
        lbase[t] = (unsigned short)lb;
        cbase[t] = (unsigned short)cb;
        if (t == NB - 1) {
            lbase[NB] = (unsigned short)sb[t].x;
            cbase[NB] = (unsigned short)sb[t].y;
        }
        for (int k = 0; k < (cap >> 4); ++k)
            line_bucket[(cb >> 4) + k] = (unsigned short)t;
        hist[t] = 0;                   // run counters
    }
    __syncthreads();

    // rank + stage into LDS
    int n4 = cnt_edges >> 2;
    const int4* s4 = (const int4*)(src + c0);
    const int4* d4 = (const int4*)(dst + c0);
    for (int g = t; g < n4; g += BLK) {
        int4 s = s4[g];
        int4 d = d4[g];
        {
            int b = d.x >> SHIFT; int r = lbase[b] + atomicAdd(&hist[b], 1);
            reorder[r] = ((unsigned)s.x << SHIFT) | ((unsigned)d.x & WMASK);
        }
        {
            int b = d.y >> SHIFT; int r = lbase[b] + atomicAdd(&hist[b], 1);
            reorder[r] = ((unsigned)s.y << SHIFT) | ((unsigned)d.y & WMASK);
        }
        {
            int b = d.z >> SHIFT; int r = lbase[b] + atomicAdd(&hist[b], 1);
            reorder[r] = ((unsigned)s.z << SHIFT) | ((unsigned)d.z & WMASK);
        }
        {
            int b = d.w >> SHIFT; int r = lbase[b] + atomicAdd(&hist[b], 1);
            reorder[r] = ((unsigned)s.w << SHIFT) | ((unsigned)d.w & WMASK);
        }
    }
    for (int i = (n4 << 2) + t; i < cnt_edges; i += BLK) {
        int dd = dst[c0 + i], ss = src[c0 + i];
        int b = dd >> SHIFT; int r = lbase[b] + atomicAdd(&hist[b], 1);
        reorder[r] = ((unsigned)ss << SHIFT) | ((unsigned)dd & WMASK);
    }
    __syncthreads();

    // linear copy-out in padded index space (full-line writes only)
    int ptot = cbase[NB];
    for (int p = t; p < ptot; p += BLK) {
        int b = line_bucket[p >> 4];
        int off = p - cbase[b];
        int cnt = lbase[b + 1] - lbase[b];
        unsigned v = (off < cnt) ? reorder[lbase[b] + off] : sentbase;
        sorted[gbase[b] + off] = v;
    }
}

// Per-bucket in-degree (skip sentinels) -> dinv, pre-quantized packed xs64.
#define NODES_PER_B (1 << SHIFT)   // 2048
__global__ __launch_bounds__(1024) void s_deg(
        const unsigned* __restrict__ sorted, const int* __restrict__ start,
        const float2* __restrict__ x, float* __restrict__ dinv,
        unsigned long long* __restrict__ xs64, int nn, unsigned sentpad) {
    __shared__ int cnt[NODES_PER_B];
    int b = blockIdx.x;
    for (int i = threadIdx.x; i < NODES_PER_B; i += blockDim.x) cnt[i] = 0;
    __syncthreads();
    int e0 = start[b], e1 = start[b + 1];
    int n4 = (e1 - e0) >> 2;
    const u32x4* sv = (const u32x4*)(sorted + e0);
    int stride2 = blockDim.x * 2;
    for (int g = threadIdx.x; g < n4; g += stride2) {
        int g2 = g + blockDim.x;
        u32x4 a = __builtin_nontemporal_load(sv + g);
        u32x4 b4 = (g2 < n4) ? __builtin_nontemporal_load(sv + g2) : (u32x4)sentpad;
        if (!(a.x >> 31)) atomicAdd(&cnt[a.x & WMASK], 1);
        if (!(a.y >> 31)) atomicAdd(&cnt[a.y & WMASK], 1);
        if (!(a.z >> 31)) atomicAdd(&cnt[a.z & WMASK], 1);
        if (!(a.w >> 31)) atomicAdd(&cnt[a.w & WMASK], 1);
        if (!(b4.x >> 31)) atomicAdd(&cnt[b4.x & WMASK], 1);
        if (!(b4.y >> 31)) atomicAdd(&cnt[b4.y & WMASK], 1);
        if (!(b4.z >> 31)) atomicAdd(&cnt[b4.z & WMASK], 1);
        if (!(b4.w >> 31)) atomicAdd(&cnt[b4.w & WMASK], 1);
    }
    __syncthreads();
    int base = b << SHIFT;
    for (int j = threadIdx.x; j < NODES_PER_B; j += blockDim.x) {
        int node = base + j;
        if (node < nn) {
            float di = rsqrtf((float)(cnt[j] + 1));   // +1 self-loop
            dinv[node] = di;
            float2 xv = x[node];
            xs64[node] = pack2(xv.x * di, xv.y * di);
        }
    }
}

// Per-bucket aggregation + fused epilogue. ONE u64 LDS atomic per edge.
// LAYER==1: A = di*(sum + self); h=relu(W1^T A+b1); out64 = pack((W2^T h)*di)
// LAYER==2: out_f2 = di*(sum + self) + b2
template <int LAYER>
__global__ __launch_bounds__(1024) void s_agg(
        const unsigned* __restrict__ sorted, const int* __restrict__ start,
        const unsigned long long* __restrict__ feat64, const float* __restrict__ dinv,
        const float* __restrict__ W1, const float* __restrict__ b1,
        const float* __restrict__ W2, const float* __restrict__ b2,
        unsigned long long* __restrict__ out64, float2* __restrict__ out_f2,
        int nn, unsigned sentpad) {
    __shared__ unsigned long long acc64[NODES_PER_B];   // 16KB
    int b = blockIdx.x;
    for (int i = threadIdx.x; i < NODES_PER_B; i += blockDim.x) acc64[i] = 0ULL;
    __syncthreads();
    int e0 = start[b], e1 = start[b + 1];
    int n4 = (e1 - e0) >> 2;
    const u32x4* sv = (const u32x4*)(sorted + e0);
    int stride2 = blockDim.x * 2;
    for (int g = threadIdx.x; g < n4; g += stride2) {
        int g2 = g + blockDim.x;
        u32x4 a = __builtin_nontemporal_load(sv + g);
        u32x4 c = (g2 < n4) ? __builtin_nontemporal_load(sv + g2) : (u32x4)sentpad;
        if (!(a.x >> 31)) atomicAdd(&acc64[a.x & WMASK], feat64[(a.x >> SHIFT) & IDXMASK]);
        if (!(a.y >> 31)) atomicAdd(&acc64[a.y & WMASK], feat64[(a.y >> SHIFT) & IDXMASK]);
        if (!(a.z >> 31)) atomicAdd(&acc64[a.z & WMASK], feat64[(a.z >> SHIFT) & IDXMASK]);
        if (!(a.w >> 31)) atomicAdd(&acc64[a.w & WMASK], feat64[(a.w >> SHIFT) & IDXMASK]);
        if (!(c.x >> 31)) atomicAdd(&acc64[c.x & WMASK], feat64[(c.x >> SHIFT) & IDXMASK]);
        if (!(c.y >> 31)) atomicAdd(&acc64[c.y & WMASK], feat64[(c.y >> SHIFT) & IDXMASK]);
        if (!(c.z >> 31)) atomicAdd(&acc64[c.z & WMASK], feat64[(c.z >> SHIFT) & IDXMASK]);
        if (!(c.w >> 31)) atomicAdd(&acc64[c.w & WMASK], feat64[(c.w >> SHIFT) & IDXMASK]);
    }
    __syncthreads();
    int base = b << SHIFT;
    for (int j = threadIdx.x; j < NODES_PER_B; j += blockDim.x) {
        int node = base + j;
        if (node >= nn) continue;
        float di = dinv[node];
        int cnt = (int)rintf(1.0f / (di * di)) - 1;   // in-degree (exact)
        unsigned long long p = acc64[j];
        unsigned long long s64 = feat64[node];
        long long bsum = (long long)(cnt) * QBIAS;
        float sx = (float)((long long)(p & 0xffffffffULL) - bsum) * (1.0f / QSCALE);
        float sy = (float)((long long)(p >> 32)           - bsum) * (1.0f / QSCALE);
        float fx = (float)((long long)(s64 & 0xffffffffULL) - QBIAS) * (1.0f / QSCALE);
        float fy = (float)((long long)(s64 >> 32)           - QBIAS) * (1.0f / QSCALE);
        float ax = di * (sx + fx);
        float ay = di * (sy + fy);
        if (LAYER == 1) {
            float o0 = 0.f, o1 = 0.f;
#pragma unroll
            for (int k = 0; k < 8; ++k) {
                float hk = fmaxf(ax * W1[k] + ay * W1[8 + k] + b1[k], 0.f);
                o0 += hk * W2[2 * k + 0];
                o1 += hk * W2[2 * k + 1];
            }
            out64[node] = pack2(o0 * di, o1 * di);
        } else {
            float2 r = make_float2(ax + b2[0], ay + b2[1]);
            __builtin_nontemporal_store(r.x, &out_f2[node].x);
            __builtin_nontemporal_store(r.y, &out_f2[node].y);
        }
    }
}

// ---------- fallback (round-1 algorithm, ~24 MB scratch) ----------

__global__ void k_deg(const int* __restrict__ dst, int* __restrict__ deg, int ne) {
    int i = blockIdx.x * blockDim.x + threadIdx.x;
    int stride = gridDim.x * blockDim.x;
    for (; i < ne; i += stride) atomicAdd(&deg[dst[i]], 1);
}
__global__ void k_dinv(const int* __restrict__ deg, float* __restrict__ dinv, int nn) {
    int i = blockIdx.x * blockDim.x + threadIdx.x;
    if (i < nn) dinv[i] = rsqrtf((float)(deg[i] + 1));
}
__global__ void k_edge2(const int* __restrict__ src, const int* __restrict__ dst,
                        const float* __restrict__ feat2, const float* __restrict__ dinv,
                        float* __restrict__ agg2, int ne) {
    int i = blockIdx.x * blockDim.x + threadIdx.x;
    int stride = gridDim.x * blockDim.x;
    for (; i < ne; i += stride) {
        int s = src[i], d = dst[i];
        float nrm = dinv[s] * dinv[d];
        float2 f = reinterpret_cast<const float2*>(feat2)[s];
        unsafeAtomicAdd(&agg2[2 * d + 0], nrm * f.x);
        unsafeAtomicAdd(&agg2[2 * d + 1], nrm * f.y);
    }
}
__global__ void k_mid(const float* __restrict__ x, const float* __restrict__ aggx,
                      const float* __restrict__ dinv,
                      const float* __restrict__ W1, const float* __restrict__ b1,
                      const float* __restrict__ W2, float* __restrict__ a2, int nn) {
    int i = blockIdx.x * blockDim.x + threadIdx.x;
    if (i >= nn) return;
    float di = dinv[i], di2 = di * di;
    float2 xsv = reinterpret_cast<const float2*>(x)[i];
    float ax = aggx[2 * i + 0] + di2 * xsv.x;
    float ay = aggx[2 * i + 1] + di2 * xsv.y;
    float o0 = 0.f, o1 = 0.f;
#pragma unroll
    for (int k = 0; k < 8; ++k) {
        float hk = fmaxf(ax * W1[k] + ay * W1[8 + k] + b1[k], 0.f);
        o0 += hk * W2[2 * k + 0];
        o1 += hk * W2[2 * k + 1];
    }
    a2[2 * i + 0] = o0;
    a2[2 * i + 1] = o1;
}
__global__ void k_out(const float* __restrict__ a2, const float* __restrict__ dinv,
                      const float* __restrict__ b2, float* __restrict__ out, int nn) {
    int i = blockIdx.x * blockDim.x + threadIdx.x;
    if (i >= nn) return;
    float di = dinv[i], di2 = di * di;
    out[2 * i + 0] = out[2 * i + 0] + di2 * a2[2 * i + 0] + b2[0];
    out[2 * i + 1] = out[2 * i + 1] + di2 * a2[2 * i + 1] + b2[1];
}

extern "C" void kernel_launch(void* const* d_in, const int* in_sizes, int n_in,
                              void* d_out, int out_size, void* d_ws, size_t ws_size,
                              hipStream_t stream) {
    const float* x  = (const float*)d_in[0];
    const int*   ei = (const int*)d_in[1];
    const float* W1 = (const float*)d_in[2];
    const float* b1 = (const float*)d_in[3];
    const float* W2 = (const float*)d_in[4];
    const float* b2 = (const float*)d_in[5];
    float* out = (float*)d_out;

    const int nn = in_sizes[0] / 2;
    const int ne = in_sizes[1] / 2;
    const int* src = ei;
    const int* dst = ei + ne;

    char* ws = (char*)d_ws;
    size_t off = 0;
    auto alloc = [&](size_t bytes) -> void* {
        void* p = ws + off;
        off += (bytes + 255) & ~size_t(255);
        return p;
    };

    int nc = (ne + EPW - 1) / EPW;
    size_t sorted_elems = (size_t)ne + (size_t)nc * NB * 16;   // worst-case pads
    size_t need = sorted_elems * 4 + (size_t)nn * 4 + 2 * ((size_t)nn + 1) * 8
                + 2 * (size_t)nc * NB * 4 + (2 * NB + 2) * 4 + 16384;

    if (ws_size >= need && nc <= 1024 && nn < (1 << 20) + 1) {
        unsigned*           sorted = (unsigned*)           alloc(sorted_elems * 4);
        float*              dinv   = (float*)              alloc((size_t)nn * 4);
        unsigned long long* xs64   = (unsigned long long*) alloc(((size_t)nn + 1) * 8);
        unsigned long long* xs2_64 = (unsigned long long*) alloc(((size_t)nn + 1) * 8);
        int*                ghist  = (int*)                alloc((size_t)nc * NB * 4);
        int*                cnts   = (int*)                alloc((size_t)nc * NB * 4);
        int*                tot    = (int*)                alloc(NB * 4);
        int*                start  = (int*)                alloc((NB + 1) * 4);

        unsigned sentbase = 0x80000000u;   // src index 0, predicated off

        h_hist   <<<nc, BLK, 0, stream>>>(dst, ne, ghist, cnts);
        h_colscan<<<NB, 256, 0, stream>>>(ghist, tot, nc);
        s_scan   <<<1, NB, 0, stream>>>(tot, start);
        h_scatter<<<nc, BLK, 0, stream>>>(src, dst, ne, ghist, cnts, start, sorted,
                                          sentbase);
        s_deg    <<<NB, 1024, 0, stream>>>(sorted, start, (const float2*)x, dinv, xs64,
                                           nn, sentbase);
        s_agg<1> <<<NB, 1024, 0, stream>>>(sorted, start, xs64, dinv, W1, b1, W2, b2,
                                           xs2_64, nullptr, nn, sentbase);
        s_agg<2> <<<NB, 1024, 0, stream>>>(sorted, start, xs2_64, dinv, W1, b1, W2, b2,
                                           nullptr, (float2*)out, nn, sentbase);
    } else {
        // fallback: round-1 algorithm
        int*   deg  = (int*)  alloc((size_t)nn * 4);
        float* dinv = (float*)alloc((size_t)nn * 4);
        float* aggx = (float*)alloc((size_t)nn * 8);
        float* a2   = (float*)alloc((size_t)nn * 8);
        hipMemsetAsync(deg,  0, (size_t)nn * 4, stream);
        hipMemsetAsync(aggx, 0, (size_t)nn * 8, stream);
        hipMemsetAsync(d_out, 0, (size_t)nn * 8, stream);
        const int TB = 256;
        int egrid = (ne + TB - 1) / TB;
        int ngrid = (nn + TB - 1) / TB;
        k_deg  <<<egrid, TB, 0, stream>>>(dst, deg, ne);
        k_dinv <<<ngrid, TB, 0, stream>>>(deg, dinv, nn);
        k_edge2<<<egrid, TB, 0, stream>>>(src, dst, x, dinv, aggx, ne);
        k_mid  <<<ngrid, TB, 0, stream>>>(x, aggx, dinv, W1, b1, W2, a2, nn);
        k_edge2<<<egrid, TB, 0, stream>>>(src, dst, a2, dinv, out, ne);
        k_out  <<<ngrid, TB, 0, stream>>>(a2, dinv, b2, out, nn);
    }
}